// Round 5
// baseline (450.392 us; speedup 1.0000x reference)
//
#include <hip/hip_runtime.h>
#include <math.h>

#define FEAT 64
#define NKERN 3

// Per-edge Gaussian kernel weights for one layer: wbuf[e, k], k=0..2.
__global__ __launch_bounds__(256) void wk_kernel(
    const float* __restrict__ pseudo,  // [E, 2]
    const float* __restrict__ projW,   // [2,2] (din,dout)
    const float* __restrict__ projB,   // [2]
    const float* __restrict__ mu,      // [3,2]
    const float* __restrict__ isg,     // [3,2]
    float* __restrict__ wbuf,          // [E, 3]
    int n_edges)
{
    int e = blockIdx.x * 256 + threadIdx.x;
    if (e >= n_edges) return;
    float2 p = ((const float2*)pseudo)[e];
    float u0 = tanhf(fmaf(p.x, projW[0], fmaf(p.y, projW[2], projB[0])));
    float u1 = tanhf(fmaf(p.x, projW[1], fmaf(p.y, projW[3], projB[1])));
    float d0, d1, s0, s1;
    d0 = u0 - mu[0]; d1 = u1 - mu[1]; s0 = isg[0]; s1 = isg[1];
    float w0 = expf(-0.5f * (d0*d0*s0*s0 + d1*d1*s1*s1));
    d0 = u0 - mu[2]; d1 = u1 - mu[3]; s0 = isg[2]; s1 = isg[3];
    float w1 = expf(-0.5f * (d0*d0*s0*s0 + d1*d1*s1*s1));
    d0 = u0 - mu[4]; d1 = u1 - mu[5]; s0 = isg[4]; s1 = isg[5];
    float w2 = expf(-0.5f * (d0*d0*s0*s0 + d1*d1*s1*s1));
    wbuf[(size_t)e * 3 + 0] = w0;
    wbuf[(size_t)e * 3 + 1] = w1;
    wbuf[(size_t)e * 3 + 2] = w2;
}

// g[n, k*64+j] = sum_{e in row(n)} wbuf[e,k] * h[colind[e], j]
// One wave per node, lane = feature j. colind/wbuf reads are wave-uniform
// s_loads; VALU work is 32 coalesced gathers + 96 v_fmac with SGPR weights.
__global__ __launch_bounds__(256) void agg_kernel(
    const float* __restrict__ h,       // [N, 64]
    const int*   __restrict__ rowptr,  // [N+1]
    const int*   __restrict__ colind,  // [E]
    const float* __restrict__ wbuf,    // [E, 3]
    float* __restrict__ g,             // [N, 192]
    int n_nodes)
{
    int lane = threadIdx.x & 63;
    int node = (int)((blockIdx.x * blockDim.x + threadIdx.x) >> 6);
    if (node >= n_nodes) return;
    int nu  = __builtin_amdgcn_readfirstlane(node);
    int r0  = rowptr[nu];
    int deg = rowptr[nu + 1] - r0;   // fixed 32 in this problem

    float a0 = 0.f, a1 = 0.f, a2 = 0.f;
    if (deg == 32) {
        #pragma unroll
        for (int ch = 0; ch < 2; ++ch) {
            int base = r0 + ch * 16;
            float v[16];
            #pragma unroll
            for (int i = 0; i < 16; ++i) {
                int cc = colind[base + i];              // uniform -> s_load
                v[i] = h[(size_t)cc * FEAT + lane];     // SGPR base + lane off
            }
            #pragma unroll
            for (int i = 0; i < 16; ++i) {
                const float* wp = wbuf + (size_t)(base + i) * 3;  // uniform
                a0 = fmaf(wp[0], v[i], a0);
                a1 = fmaf(wp[1], v[i], a1);
                a2 = fmaf(wp[2], v[i], a2);
            }
        }
    } else {
        for (int i = 0; i < deg; ++i) {
            int cc = colind[r0 + i];
            float vv = h[(size_t)cc * FEAT + lane];
            const float* wp = wbuf + (size_t)(r0 + i) * 3;
            a0 = fmaf(wp[0], vv, a0);
            a1 = fmaf(wp[1], vv, a1);
            a2 = fmaf(wp[2], vv, a2);
        }
    }
    float* gp = g + (size_t)node * (NKERN * FEAT);
    gp[lane]            = a0;
    gp[FEAT + lane]     = a1;
    gp[2 * FEAT + lane] = a2;
}

// out[n, f] = sum_jp g[n, jp] * fcW[jp&63, (jp>>6)*64 + f]
// lane = row; each wave computes ALL 64 f for its 64 rows (acc[64]).
// W addresses are thread-independent -> scalarized s_load, consumed as the
// SGPR operand of v_fmac. 256 FMAs per 64 W-dwords + 1 g-float4 => FMA-bound.
// Grid 196 blocks: every CU <= 1 block, 1 wave/SIMD, ~24.6k FMA cyc each.
__global__ __launch_bounds__(256) void gemm_kernel(
    const float* __restrict__ g,    // [N, 192]
    const float* __restrict__ fcW,  // [64, 192] this layer
    float* __restrict__ out,        // [N, 64]
    int n_nodes)
{
    int row  = blockIdx.x * 256 + threadIdx.x;
    int rowc = row < n_nodes ? row : n_nodes - 1;   // clamp loads, guard store
    const float4* grow4 = (const float4*)(g + (size_t)rowc * 192);

    float acc[64];
    #pragma unroll
    for (int i = 0; i < 64; ++i) acc[i] = 0.f;

    for (int jp4 = 0; jp4 < 48; ++jp4) {
        float4 gv = grow4[jp4];
        int k = jp4 >> 4;            // kernel block (uniform)
        int j = (jp4 & 15) * 4;      // W row within block (uniform)
        const float* wb = fcW + (size_t)(j * 192 + k * 64);
        #pragma unroll
        for (int i = 0; i < 4; ++i) {
            float gvi = (i == 0) ? gv.x : (i == 1) ? gv.y : (i == 2) ? gv.z : gv.w;
            const float4* wr = (const float4*)(wb + i * 192);   // uniform -> s_load
            #pragma unroll
            for (int f4 = 0; f4 < 16; ++f4) {
                float4 wv = wr[f4];
                acc[f4 * 4 + 0] = fmaf(gvi, wv.x, acc[f4 * 4 + 0]);
                acc[f4 * 4 + 1] = fmaf(gvi, wv.y, acc[f4 * 4 + 1]);
                acc[f4 * 4 + 2] = fmaf(gvi, wv.z, acc[f4 * 4 + 2]);
                acc[f4 * 4 + 3] = fmaf(gvi, wv.w, acc[f4 * 4 + 3]);
            }
        }
    }

    if (row < n_nodes) {
        float4* orow = (float4*)(out + (size_t)row * 64);
        #pragma unroll
        for (int f4 = 0; f4 < 16; ++f4)
            orow[f4] = make_float4(acc[f4 * 4 + 0], acc[f4 * 4 + 1],
                                   acc[f4 * 4 + 2], acc[f4 * 4 + 3]);
    }
}

extern "C" void kernel_launch(void* const* d_in, const int* in_sizes, int n_in,
                              void* d_out, int out_size, void* d_ws, size_t ws_size,
                              hipStream_t stream)
{
    const float* feat   = (const float*)d_in[0];   // [N, 64]
    const float* pseudo = (const float*)d_in[1];   // [E, 2]
    const int*   rowptr = (const int*)d_in[2];     // [N+1]
    const int*   colind = (const int*)d_in[3];     // [E]
    const float* projW  = (const float*)d_in[4];   // [L, 2, 2]
    const float* projB  = (const float*)d_in[5];   // [L, 2]
    const float* fcW    = (const float*)d_in[6];   // [L, 64, 192]
    const float* mu     = (const float*)d_in[7];   // [L, 3, 2]
    const float* isg    = (const float*)d_in[8];   // [L, 3, 2]
    float* out = (float*)d_out;

    int n = in_sizes[0] / FEAT;                         // 50000
    int e = in_sizes[3];                                // 1.6M
    int n_layers = in_sizes[6] / (FEAT * NKERN * FEAT); // 3

    float* gbuf = (float*)d_ws;                       // n * 192 floats
    float* hbuf = gbuf + (size_t)n * NKERN * FEAT;    // n * 64 floats
    float* wbuf = hbuf + (size_t)n * FEAT;            // e * 3 floats

    dim3 blk(256);
    dim3 wkGrid((e + 255) / 256);
    dim3 aggGrid((n + 3) / 4);
    dim3 gemmGrid((n + 255) / 256);

    const float* hin = feat;
    for (int l = 0; l < n_layers; ++l) {
        float* hout = (l == n_layers - 1) ? out : hbuf;
        wk_kernel<<<wkGrid, blk, 0, stream>>>(
            pseudo, projW + (size_t)l * 4, projB + (size_t)l * 2,
            mu + (size_t)l * 6, isg + (size_t)l * 6, wbuf, e);
        agg_kernel<<<aggGrid, blk, 0, stream>>>(
            hin, rowptr, colind, wbuf, gbuf, n);
        gemm_kernel<<<gemmGrid, blk, 0, stream>>>(
            gbuf, fcW + (size_t)l * FEAT * NKERN * FEAT, hout, n);
        hin = hbuf;
    }
}

// Round 6
// 353.525 us; speedup vs baseline: 1.2740x; 1.2740x over previous
//
#include <hip/hip_runtime.h>
#include <math.h>

#define FEAT 64
#define NKERN 3

// Per-edge Gaussian kernel weights for one layer: wbuf[e, k], k=0..2.
__global__ __launch_bounds__(256) void wk_kernel(
    const float* __restrict__ pseudo,  // [E, 2]
    const float* __restrict__ projW,   // [2,2] (din,dout)
    const float* __restrict__ projB,   // [2]
    const float* __restrict__ mu,      // [3,2]
    const float* __restrict__ isg,     // [3,2]
    float* __restrict__ wbuf,          // [E, 3]
    int n_edges)
{
    int e = blockIdx.x * 256 + threadIdx.x;
    if (e >= n_edges) return;
    float2 p = ((const float2*)pseudo)[e];
    float u0 = tanhf(fmaf(p.x, projW[0], fmaf(p.y, projW[2], projB[0])));
    float u1 = tanhf(fmaf(p.x, projW[1], fmaf(p.y, projW[3], projB[1])));
    float d0, d1, s0, s1;
    d0 = u0 - mu[0]; d1 = u1 - mu[1]; s0 = isg[0]; s1 = isg[1];
    float w0 = expf(-0.5f * (d0*d0*s0*s0 + d1*d1*s1*s1));
    d0 = u0 - mu[2]; d1 = u1 - mu[3]; s0 = isg[2]; s1 = isg[3];
    float w1 = expf(-0.5f * (d0*d0*s0*s0 + d1*d1*s1*s1));
    d0 = u0 - mu[4]; d1 = u1 - mu[5]; s0 = isg[4]; s1 = isg[5];
    float w2 = expf(-0.5f * (d0*d0*s0*s0 + d1*d1*s1*s1));
    wbuf[(size_t)e * 3 + 0] = w0;
    wbuf[(size_t)e * 3 + 1] = w1;
    wbuf[(size_t)e * 3 + 2] = w2;
}

// gT[k*64+j][n] = sum_{e in row(n)} wbuf[e,k] * h[colind[e], j]
// Block = 16 nodes (4 waves x 4 serial nodes). lane = feature j; colind/wbuf
// via wave-uniform s_loads; gathers coalesced 256B. Results transposed
// through LDS (pad 17) and written to gT with 64B-contiguous segments.
__global__ __launch_bounds__(256) void agg_kernel(
    const float* __restrict__ h,       // [N, 64]
    const int*   __restrict__ rowptr,  // [N+1]
    const int*   __restrict__ colind,  // [E]
    const float* __restrict__ wbuf,    // [E, 3]
    float* __restrict__ gT,            // [192, np]
    int n_nodes, int np)
{
    __shared__ float tile[NKERN * FEAT * 17];   // [192][17] ~13 KB
    int tid  = threadIdx.x;
    int lane = tid & 63;
    int wv   = tid >> 6;            // 0..3
    int n0   = blockIdx.x * 16;

    #pragma unroll
    for (int m = 0; m < 4; ++m) {
        int node = n0 + wv * 4 + m;                      // wave-uniform
        float a0 = 0.f, a1 = 0.f, a2 = 0.f;
        if (node < n_nodes) {
            int nu  = __builtin_amdgcn_readfirstlane(node);
            int r0  = rowptr[nu];
            int deg = rowptr[nu + 1] - r0;               // fixed 32 here
            if (deg == 32) {
                #pragma unroll
                for (int ch = 0; ch < 2; ++ch) {
                    int base = r0 + ch * 16;
                    float v[16];
                    #pragma unroll
                    for (int i = 0; i < 16; ++i) {
                        int cc = colind[base + i];           // uniform -> s_load
                        v[i] = h[(size_t)cc * FEAT + lane];  // coalesced 256B
                    }
                    #pragma unroll
                    for (int i = 0; i < 16; ++i) {
                        const float* wp = wbuf + (size_t)(base + i) * 3;
                        a0 = fmaf(wp[0], v[i], a0);
                        a1 = fmaf(wp[1], v[i], a1);
                        a2 = fmaf(wp[2], v[i], a2);
                    }
                }
            } else {
                for (int i = 0; i < deg; ++i) {
                    int cc = colind[r0 + i];
                    float vv = h[(size_t)cc * FEAT + lane];
                    const float* wp = wbuf + (size_t)(r0 + i) * 3;
                    a0 = fmaf(wp[0], vv, a0);
                    a1 = fmaf(wp[1], vv, a1);
                    a2 = fmaf(wp[2], vv, a2);
                }
            }
        }
        int col = wv * 4 + m;
        tile[(0 * FEAT + lane) * 17 + col] = a0;   // jp = k*64 + lane
        tile[(1 * FEAT + lane) * 17 + col] = a1;
        tile[(2 * FEAT + lane) * 17 + col] = a2;
    }
    __syncthreads();

    int nrem = n_nodes - n0; if (nrem > 16) nrem = 16;
    int idx = tid & 15;
    int jp0 = tid >> 4;     // 0..15
    #pragma unroll
    for (int rep = 0; rep < 12; ++rep) {
        int jp = jp0 + rep * 16;
        if (idx < nrem)
            gT[(size_t)jp * np + n0 + idx] = tile[jp * 17 + idx];
    }
}

// out[n, f] = sum_jp gT[jp][n] * Wcat[jp, f], Wcat[k*64+j][f] = fcW[j, k*64+f].
// lane = row (coalesced gT reads); wave w covers f in [16w, 16w+16), acc[16].
// W reads are wave-uniform -> s_load (scalar pipe), consumed as SGPR operand.
__global__ __launch_bounds__(256) void gemm_kernel(
    const float* __restrict__ gT,   // [192, np]
    const float* __restrict__ fcW,  // [64, 192] this layer
    float* __restrict__ out,        // [N, 64]
    int n_nodes, int np)
{
    int tid  = threadIdx.x;
    int lane = tid & 63;
    int f0   = __builtin_amdgcn_readfirstlane((tid >> 6) * 16);
    int row  = blockIdx.x * 64 + lane;
    const float* gcol = gT + (size_t)blockIdx.x * 64 + lane;

    float acc[16];
    #pragma unroll
    for (int i = 0; i < 16; ++i) acc[i] = 0.f;

    #pragma unroll 2
    for (int j = 0; j < 64; ++j) {
        #pragma unroll
        for (int k = 0; k < 3; ++k) {
            int jp = k * 64 + j;
            float gv = gcol[(size_t)jp * np];                 // coalesced 256B
            const float* wr = fcW + j * 192 + k * 64 + f0;    // uniform -> s_load
            float4 wa = *(const float4*)(wr + 0);
            float4 wb = *(const float4*)(wr + 4);
            float4 wc = *(const float4*)(wr + 8);
            float4 wd = *(const float4*)(wr + 12);
            acc[0]  = fmaf(gv, wa.x, acc[0]);
            acc[1]  = fmaf(gv, wa.y, acc[1]);
            acc[2]  = fmaf(gv, wa.z, acc[2]);
            acc[3]  = fmaf(gv, wa.w, acc[3]);
            acc[4]  = fmaf(gv, wb.x, acc[4]);
            acc[5]  = fmaf(gv, wb.y, acc[5]);
            acc[6]  = fmaf(gv, wb.z, acc[6]);
            acc[7]  = fmaf(gv, wb.w, acc[7]);
            acc[8]  = fmaf(gv, wc.x, acc[8]);
            acc[9]  = fmaf(gv, wc.y, acc[9]);
            acc[10] = fmaf(gv, wc.z, acc[10]);
            acc[11] = fmaf(gv, wc.w, acc[11]);
            acc[12] = fmaf(gv, wd.x, acc[12]);
            acc[13] = fmaf(gv, wd.y, acc[13]);
            acc[14] = fmaf(gv, wd.z, acc[14]);
            acc[15] = fmaf(gv, wd.w, acc[15]);
        }
    }

    if (row < n_nodes) {
        float4* orow = (float4*)(out + (size_t)row * 64 + f0);
        orow[0] = make_float4(acc[0],  acc[1],  acc[2],  acc[3]);
        orow[1] = make_float4(acc[4],  acc[5],  acc[6],  acc[7]);
        orow[2] = make_float4(acc[8],  acc[9],  acc[10], acc[11]);
        orow[3] = make_float4(acc[12], acc[13], acc[14], acc[15]);
    }
}

extern "C" void kernel_launch(void* const* d_in, const int* in_sizes, int n_in,
                              void* d_out, int out_size, void* d_ws, size_t ws_size,
                              hipStream_t stream)
{
    const float* feat   = (const float*)d_in[0];   // [N, 64]
    const float* pseudo = (const float*)d_in[1];   // [E, 2]
    const int*   rowptr = (const int*)d_in[2];     // [N+1]
    const int*   colind = (const int*)d_in[3];     // [E]
    const float* projW  = (const float*)d_in[4];   // [L, 2, 2]
    const float* projB  = (const float*)d_in[5];   // [L, 2]
    const float* fcW    = (const float*)d_in[6];   // [L, 64, 192]
    const float* mu     = (const float*)d_in[7];   // [L, 3, 2]
    const float* isg    = (const float*)d_in[8];   // [L, 3, 2]
    float* out = (float*)d_out;

    int n  = in_sizes[0] / FEAT;                        // 50000
    int e  = in_sizes[3];                               // 1.6M
    int n_layers = in_sizes[6] / (FEAT * NKERN * FEAT); // 3
    int np = (n + 63) & ~63;                            // 50048 (256B-aligned rows)

    float* gbuf = (float*)d_ws;                        // np * 192 floats (gT)
    float* hbuf = gbuf + (size_t)np * NKERN * FEAT;    // n * 64 floats
    float* wbuf = hbuf + (size_t)n * FEAT;             // e * 3 floats

    dim3 blk(256);
    dim3 wkGrid((e + 255) / 256);
    dim3 aggGrid((n + 15) / 16);
    dim3 gemmGrid((n + 63) / 64);

    const float* hin = feat;
    for (int l = 0; l < n_layers; ++l) {
        float* hout = (l == n_layers - 1) ? out : hbuf;
        wk_kernel<<<wkGrid, blk, 0, stream>>>(
            pseudo, projW + (size_t)l * 4, projB + (size_t)l * 2,
            mu + (size_t)l * 6, isg + (size_t)l * 6, wbuf, e);
        agg_kernel<<<aggGrid, blk, 0, stream>>>(
            hin, rowptr, colind, wbuf, gbuf, n, np);
        gemm_kernel<<<gemmGrid, blk, 0, stream>>>(
            gbuf, fcW + (size_t)l * FEAT * NKERN * FEAT, hout, n, np);
        hin = hbuf;
    }
}

// Round 7
// 340.308 us; speedup vs baseline: 1.3235x; 1.0388x over previous
//
#include <hip/hip_runtime.h>
#include <math.h>

#define FEAT 64
#define NKERN 3

__device__ __forceinline__ unsigned short f2bf(float f) {
    unsigned int u = __float_as_uint(f);
    u = (u + 0x7fffu + ((u >> 16) & 1u)) >> 16;   // round-to-nearest-even
    return (unsigned short)u;
}
__device__ __forceinline__ float bf2f(unsigned short b) {
    return __uint_as_float(((unsigned int)b) << 16);
}

// feat (fp32) -> bf16, 4 elems/thread
__global__ __launch_bounds__(256) void cast_kernel(
    const float* __restrict__ x, unsigned short* __restrict__ y, int n4)
{
    int i = blockIdx.x * 256 + threadIdx.x;
    if (i >= n4) return;
    float4 v = ((const float4*)x)[i];
    ushort4 o;
    o.x = f2bf(v.x); o.y = f2bf(v.y); o.z = f2bf(v.z); o.w = f2bf(v.w);
    ((ushort4*)y)[i] = o;
}

// Per-edge Gaussian kernel weights for one layer: wbuf[e, k], k=0..2.
__global__ __launch_bounds__(256) void wk_kernel(
    const float* __restrict__ pseudo,  // [E, 2]
    const float* __restrict__ projW,   // [2,2] (din,dout)
    const float* __restrict__ projB,   // [2]
    const float* __restrict__ mu,      // [3,2]
    const float* __restrict__ isg,     // [3,2]
    float* __restrict__ wbuf,          // [E, 3]
    int n_edges)
{
    int e = blockIdx.x * 256 + threadIdx.x;
    if (e >= n_edges) return;
    float2 p = ((const float2*)pseudo)[e];
    float u0 = tanhf(fmaf(p.x, projW[0], fmaf(p.y, projW[2], projB[0])));
    float u1 = tanhf(fmaf(p.x, projW[1], fmaf(p.y, projW[3], projB[1])));
    float d0, d1, s0, s1;
    d0 = u0 - mu[0]; d1 = u1 - mu[1]; s0 = isg[0]; s1 = isg[1];
    float w0 = expf(-0.5f * (d0*d0*s0*s0 + d1*d1*s1*s1));
    d0 = u0 - mu[2]; d1 = u1 - mu[3]; s0 = isg[2]; s1 = isg[3];
    float w1 = expf(-0.5f * (d0*d0*s0*s0 + d1*d1*s1*s1));
    d0 = u0 - mu[4]; d1 = u1 - mu[5]; s0 = isg[4]; s1 = isg[5];
    float w2 = expf(-0.5f * (d0*d0*s0*s0 + d1*d1*s1*s1));
    wbuf[(size_t)e * 3 + 0] = w0;
    wbuf[(size_t)e * 3 + 1] = w1;
    wbuf[(size_t)e * 3 + 2] = w2;
}

// g_blk[b][jp][i] = sum_{e in row(n=64b+i)} wbuf[e,k] * h[colind[e], j], jp=k*64+j
// Block = 16 nodes (4 waves x 4 serial nodes). lane = feature j. h is bf16
// (halved gather traffic, 6.4MB working set). colind/wbuf via wave-uniform
// s_loads; 32 gathers in flight. LDS transpose (pad 17) -> blocked gT.
__global__ __launch_bounds__(256) void agg_kernel(
    const unsigned short* __restrict__ h,  // [N, 64] bf16
    const int*   __restrict__ rowptr,      // [N+1]
    const int*   __restrict__ colind,      // [E]
    const float* __restrict__ wbuf,        // [E, 3]
    float* __restrict__ gT,                // [nblk][192][64]
    int n_nodes)
{
    __shared__ float tile[NKERN * FEAT * 17];   // [192][17] ~13 KB
    int tid  = threadIdx.x;
    int lane = tid & 63;
    int wv   = tid >> 6;            // 0..3
    int n0   = blockIdx.x * 16;

    #pragma unroll
    for (int m = 0; m < 4; ++m) {
        int node = n0 + wv * 4 + m;                      // wave-uniform
        float a0 = 0.f, a1 = 0.f, a2 = 0.f;
        if (node < n_nodes) {
            int nu  = __builtin_amdgcn_readfirstlane(node);
            int r0  = rowptr[nu];
            int deg = rowptr[nu + 1] - r0;               // fixed 32 here
            if (deg == 32) {
                unsigned short v[32];
                #pragma unroll
                for (int i = 0; i < 32; ++i) {
                    int cc = colind[r0 + i];             // uniform -> s_load
                    v[i] = h[(size_t)cc * FEAT + lane];  // coalesced 128B
                }
                #pragma unroll
                for (int i = 0; i < 32; ++i) {
                    const float* wp = wbuf + (size_t)(r0 + i) * 3;  // uniform
                    float vf = bf2f(v[i]);
                    a0 = fmaf(wp[0], vf, a0);
                    a1 = fmaf(wp[1], vf, a1);
                    a2 = fmaf(wp[2], vf, a2);
                }
            } else {
                for (int i = 0; i < deg; ++i) {
                    int cc = colind[r0 + i];
                    float vf = bf2f(h[(size_t)cc * FEAT + lane]);
                    const float* wp = wbuf + (size_t)(r0 + i) * 3;
                    a0 = fmaf(wp[0], vf, a0);
                    a1 = fmaf(wp[1], vf, a1);
                    a2 = fmaf(wp[2], vf, a2);
                }
            }
        }
        int col = wv * 4 + m;
        tile[(0 * FEAT + lane) * 17 + col] = a0;   // jp = k*64 + lane
        tile[(1 * FEAT + lane) * 17 + col] = a1;
        tile[(2 * FEAT + lane) * 17 + col] = a2;
    }
    __syncthreads();

    int nrem = n_nodes - n0; if (nrem > 16) nrem = 16;
    int idx = tid & 15;
    int jp0 = tid >> 4;     // 0..15
    size_t base = ((size_t)(n0 >> 6) * 192) * 64 + (n0 & 63);
    #pragma unroll
    for (int rep = 0; rep < 12; ++rep) {
        int jp = jp0 + rep * 16;
        if (idx < nrem)
            gT[base + (size_t)jp * 64 + idx] = tile[jp * 17 + idx];
    }
}

// out[row, f] = sum_jp g_blk[b][jp][row&63] * fcW[jp&63, (jp>>6)*64 + f]
// lane = row. Each block reads ONE contiguous 48KB g chunk (line-exact,
// page-local). W: per j the 3 k-slices are one contiguous fcW row ->
// merged wave-uniform s_loads feeding v_fmac's SGPR operand.
// last_layer: write fp32 to out; else bf16 to hnext.
__global__ __launch_bounds__(256) void gemm_kernel(
    const float* __restrict__ gT,      // [nblk][192][64]
    const float* __restrict__ fcW,     // [64, 192] this layer
    float* __restrict__ out,           // [N, 64] fp32 (last layer)
    unsigned short* __restrict__ hnext,// [N, 64] bf16 (mid layers)
    int n_nodes, int last_layer)
{
    int tid  = threadIdx.x;
    int lane = tid & 63;
    int f0   = __builtin_amdgcn_readfirstlane((tid >> 6) * 16);
    int row  = blockIdx.x * 64 + lane;
    const float* gc = gT + (size_t)blockIdx.x * (192 * 64) + lane;

    float acc[16];
    #pragma unroll
    for (int i = 0; i < 16; ++i) acc[i] = 0.f;

    #pragma unroll 2
    for (int j = 0; j < 64; ++j) {
        float g0 = gc[j * 64];              // jp = j
        float g1 = gc[j * 64 + 4096];       // jp = 64 + j
        float g2 = gc[j * 64 + 8192];       // jp = 128 + j
        const float* wr = fcW + j * 192 + f0;   // uniform -> s_load
        #pragma unroll
        for (int k = 0; k < 3; ++k) {
            float gv = (k == 0) ? g0 : (k == 1) ? g1 : g2;
            const float4* w4 = (const float4*)(wr + k * 64);
            float4 wa = w4[0];
            float4 wb = w4[1];
            float4 wc = w4[2];
            float4 wd = w4[3];
            acc[0]  = fmaf(gv, wa.x, acc[0]);
            acc[1]  = fmaf(gv, wa.y, acc[1]);
            acc[2]  = fmaf(gv, wa.z, acc[2]);
            acc[3]  = fmaf(gv, wa.w, acc[3]);
            acc[4]  = fmaf(gv, wb.x, acc[4]);
            acc[5]  = fmaf(gv, wb.y, acc[5]);
            acc[6]  = fmaf(gv, wb.z, acc[6]);
            acc[7]  = fmaf(gv, wb.w, acc[7]);
            acc[8]  = fmaf(gv, wc.x, acc[8]);
            acc[9]  = fmaf(gv, wc.y, acc[9]);
            acc[10] = fmaf(gv, wc.z, acc[10]);
            acc[11] = fmaf(gv, wc.w, acc[11]);
            acc[12] = fmaf(gv, wd.x, acc[12]);
            acc[13] = fmaf(gv, wd.y, acc[13]);
            acc[14] = fmaf(gv, wd.z, acc[14]);
            acc[15] = fmaf(gv, wd.w, acc[15]);
        }
    }

    if (row < n_nodes) {
        if (last_layer) {
            float4* orow = (float4*)(out + (size_t)row * 64 + f0);
            orow[0] = make_float4(acc[0],  acc[1],  acc[2],  acc[3]);
            orow[1] = make_float4(acc[4],  acc[5],  acc[6],  acc[7]);
            orow[2] = make_float4(acc[8],  acc[9],  acc[10], acc[11]);
            orow[3] = make_float4(acc[12], acc[13], acc[14], acc[15]);
        } else {
            uint4 p0, p1;
            p0.x = (unsigned)f2bf(acc[0])  | ((unsigned)f2bf(acc[1])  << 16);
            p0.y = (unsigned)f2bf(acc[2])  | ((unsigned)f2bf(acc[3])  << 16);
            p0.z = (unsigned)f2bf(acc[4])  | ((unsigned)f2bf(acc[5])  << 16);
            p0.w = (unsigned)f2bf(acc[6])  | ((unsigned)f2bf(acc[7])  << 16);
            p1.x = (unsigned)f2bf(acc[8])  | ((unsigned)f2bf(acc[9])  << 16);
            p1.y = (unsigned)f2bf(acc[10]) | ((unsigned)f2bf(acc[11]) << 16);
            p1.z = (unsigned)f2bf(acc[12]) | ((unsigned)f2bf(acc[13]) << 16);
            p1.w = (unsigned)f2bf(acc[14]) | ((unsigned)f2bf(acc[15]) << 16);
            uint4* orow = (uint4*)(hnext + (size_t)row * 64 + f0);
            orow[0] = p0;
            orow[1] = p1;
        }
    }
}

extern "C" void kernel_launch(void* const* d_in, const int* in_sizes, int n_in,
                              void* d_out, int out_size, void* d_ws, size_t ws_size,
                              hipStream_t stream)
{
    const float* feat   = (const float*)d_in[0];   // [N, 64]
    const float* pseudo = (const float*)d_in[1];   // [E, 2]
    const int*   rowptr = (const int*)d_in[2];     // [N+1]
    const int*   colind = (const int*)d_in[3];     // [E]
    const float* projW  = (const float*)d_in[4];   // [L, 2, 2]
    const float* projB  = (const float*)d_in[5];   // [L, 2]
    const float* fcW    = (const float*)d_in[6];   // [L, 64, 192]
    const float* mu     = (const float*)d_in[7];   // [L, 3, 2]
    const float* isg    = (const float*)d_in[8];   // [L, 3, 2]
    float* out = (float*)d_out;

    int n  = in_sizes[0] / FEAT;                        // 50000
    int e  = in_sizes[3];                               // 1.6M
    int n_layers = in_sizes[6] / (FEAT * NKERN * FEAT); // 3
    int nblk = (n + 63) / 64;                           // 782

    float* gbuf = (float*)d_ws;                                   // nblk*192*64 f
    unsigned short* hbA = (unsigned short*)(gbuf + (size_t)nblk * 192 * 64);
    unsigned short* hbB = hbA + (size_t)n * FEAT;
    float* wbuf = (float*)(hbB + (size_t)n * FEAT);               // e*3 f

    dim3 blk(256);
    dim3 castGrid((n * FEAT / 4 + 255) / 256);
    dim3 wkGrid((e + 255) / 256);
    dim3 aggGrid((n + 15) / 16);
    dim3 gemmGrid(nblk);

    cast_kernel<<<castGrid, blk, 0, stream>>>(feat, hbA, n * FEAT / 4);

    const unsigned short* hin = hbA;
    for (int l = 0; l < n_layers; ++l) {
        int last = (l == n_layers - 1);
        unsigned short* hb_out = (l == 0) ? hbB : hbA;
        wk_kernel<<<wkGrid, blk, 0, stream>>>(
            pseudo, projW + (size_t)l * 4, projB + (size_t)l * 2,
            mu + (size_t)l * 6, isg + (size_t)l * 6, wbuf, e);
        agg_kernel<<<aggGrid, blk, 0, stream>>>(
            hin, rowptr, colind, wbuf, gbuf, n);
        gemm_kernel<<<gemmGrid, blk, 0, stream>>>(
            gbuf, fcW + (size_t)l * FEAT * NKERN * FEAT, out, hb_out, n, last);
        hin = hb_out;
    }
}

// Round 8
// 317.726 us; speedup vs baseline: 1.4175x; 1.0711x over previous
//
#include <hip/hip_runtime.h>
#include <math.h>

#define FEAT 64
#define NKERN 3

typedef __attribute__((ext_vector_type(8))) short short8;
typedef __attribute__((ext_vector_type(4))) float float4v;

__device__ __forceinline__ unsigned short f2bf(float f) {
    unsigned int u = __float_as_uint(f);
    u = (u + 0x7fffu + ((u >> 16) & 1u)) >> 16;   // round-to-nearest-even
    return (unsigned short)u;
}
__device__ __forceinline__ float bf2f(unsigned short b) {
    return __uint_as_float(((unsigned int)b) << 16);
}

// feat (fp32) -> bf16, 4 elems/thread
__global__ __launch_bounds__(256) void cast_kernel(
    const float* __restrict__ x, unsigned short* __restrict__ y, int n4)
{
    int i = blockIdx.x * 256 + threadIdx.x;
    if (i >= n4) return;
    float4 v = ((const float4*)x)[i];
    ushort4 o;
    o.x = f2bf(v.x); o.y = f2bf(v.y); o.z = f2bf(v.z); o.w = f2bf(v.w);
    ((ushort4*)y)[i] = o;
}

// fcW[l][j][k*64+f] -> Wt_hi/lo[l][f][jp], jp = k*64+j  (bf16 hi + residual lo)
__global__ __launch_bounds__(256) void wprep_kernel(
    const float* __restrict__ fcW,
    unsigned short* __restrict__ Wth, unsigned short* __restrict__ Wtl,
    int total)  // L*64*192
{
    int idx = blockIdx.x * 256 + threadIdx.x;
    if (idx >= total) return;
    int l   = idx / (FEAT * 192);
    int rem = idx - l * (FEAT * 192);
    int f   = rem / 192;
    int jp  = rem - f * 192;
    int k = jp >> 6, j = jp & 63;
    float v = fcW[(size_t)l * 12288 + j * 192 + k * 64 + f];
    unsigned short hi = f2bf(v);
    Wth[idx] = hi;
    Wtl[idx] = f2bf(v - bf2f(hi));
}

// Per-edge Gaussian kernel weights for one layer: wbuf[e, k], k=0..2.
__global__ __launch_bounds__(256) void wk_kernel(
    const float* __restrict__ pseudo,  // [E, 2]
    const float* __restrict__ projW,   // [2,2] (din,dout)
    const float* __restrict__ projB,   // [2]
    const float* __restrict__ mu,      // [3,2]
    const float* __restrict__ isg,     // [3,2]
    float* __restrict__ wbuf,          // [E, 3]
    int n_edges)
{
    int e = blockIdx.x * 256 + threadIdx.x;
    if (e >= n_edges) return;
    float2 p = ((const float2*)pseudo)[e];
    float u0 = tanhf(fmaf(p.x, projW[0], fmaf(p.y, projW[2], projB[0])));
    float u1 = tanhf(fmaf(p.x, projW[1], fmaf(p.y, projW[3], projB[1])));
    float d0, d1, s0, s1;
    d0 = u0 - mu[0]; d1 = u1 - mu[1]; s0 = isg[0]; s1 = isg[1];
    float w0 = expf(-0.5f * (d0*d0*s0*s0 + d1*d1*s1*s1));
    d0 = u0 - mu[2]; d1 = u1 - mu[3]; s0 = isg[2]; s1 = isg[3];
    float w1 = expf(-0.5f * (d0*d0*s0*s0 + d1*d1*s1*s1));
    d0 = u0 - mu[4]; d1 = u1 - mu[5]; s0 = isg[4]; s1 = isg[5];
    float w2 = expf(-0.5f * (d0*d0*s0*s0 + d1*d1*s1*s1));
    wbuf[(size_t)e * 3 + 0] = w0;
    wbuf[(size_t)e * 3 + 1] = w1;
    wbuf[(size_t)e * 3 + 2] = w2;
}

// g[n][jp] = sum_{e in row(n)} wbuf[e,k] * h[colind[e], j], jp = k*64+j.
// ONE WAVE PER NODE, lane = feature j. No LDS, no barrier; row-major bf16
// hi/lo output with coalesced 128B stores. colind/wbuf via wave-uniform
// s_loads; 32 gathers in flight per wave; 6 waves/SIMD min occupancy.
__global__ __launch_bounds__(256, 6) void agg_kernel(
    const unsigned short* __restrict__ h,  // [N, 64] bf16
    const int*   __restrict__ rowptr,      // [N+1]
    const int*   __restrict__ colind,      // [E]
    const float* __restrict__ wbuf,        // [E, 3]
    unsigned short* __restrict__ ghi,      // [N, 192] bf16 hi
    unsigned short* __restrict__ glo,      // [N, 192] bf16 lo
    int n_nodes)
{
    int lane = threadIdx.x & 63;
    int node = blockIdx.x * 4 + (threadIdx.x >> 6);
    if (node >= n_nodes) return;
    int nu  = __builtin_amdgcn_readfirstlane(node);
    int r0  = rowptr[nu];
    int deg = rowptr[nu + 1] - r0;   // fixed 32 in this problem

    float a0 = 0.f, a1 = 0.f, a2 = 0.f;
    if (deg == 32) {
        unsigned short v[32];
        #pragma unroll
        for (int i = 0; i < 32; ++i) {
            int cc = colind[r0 + i];             // uniform -> s_load
            v[i] = h[(size_t)cc * FEAT + lane];  // coalesced 128B gather
        }
        #pragma unroll
        for (int i = 0; i < 32; ++i) {
            const float* wp = wbuf + (size_t)(r0 + i) * 3;  // uniform s_load
            float vf = bf2f(v[i]);
            a0 = fmaf(wp[0], vf, a0);
            a1 = fmaf(wp[1], vf, a1);
            a2 = fmaf(wp[2], vf, a2);
        }
    } else {
        for (int i = 0; i < deg; ++i) {
            int cc = colind[r0 + i];
            float vf = bf2f(h[(size_t)cc * FEAT + lane]);
            const float* wp = wbuf + (size_t)(r0 + i) * 3;
            a0 = fmaf(wp[0], vf, a0);
            a1 = fmaf(wp[1], vf, a1);
            a2 = fmaf(wp[2], vf, a2);
        }
    }
    size_t base = (size_t)node * 192;
    unsigned short h0 = f2bf(a0), h1 = f2bf(a1), h2 = f2bf(a2);
    ghi[base + lane]       = h0;
    ghi[base + 64 + lane]  = h1;
    ghi[base + 128 + lane] = h2;
    glo[base + lane]       = f2bf(a0 - bf2f(h0));
    glo[base + 64 + lane]  = f2bf(a1 - bf2f(h1));
    glo[base + 128 + lane] = f2bf(a2 - bf2f(h2));
}

// out[row, f] = sum_jp g[row][jp] * Wt[f][jp] via MFMA 16x16x32 bf16.
// Block = 4 waves = 64 rows; wave handles 16 rows x 64 f (4 f-tiles).
// hi/lo split on BOTH g and W: acc += Ahi*Bhi + Alo*Bhi + Ahi*Blo
// (error ~fp32; only h-gather bf16 approx remains in the net).
// A-frag: lane(m=lane&15,q=lane>>4) reads g[row0+m][ks*32+q*8..+8] (16B).
// B-frag: same pattern on Wt[ft*16+m][...]. C/D: col=lane&15, row=q*4+reg.
__global__ __launch_bounds__(256) void gemm_kernel(
    const unsigned short* __restrict__ ghi,  // [N,192] bf16
    const unsigned short* __restrict__ glo,  // [N,192] bf16
    const unsigned short* __restrict__ Wth,  // [64][192] bf16 (this layer)
    const unsigned short* __restrict__ Wtl,  // [64][192] bf16
    float* __restrict__ out,                 // [N,64] fp32 (last layer)
    unsigned short* __restrict__ hnext,      // [N,64] bf16 (mid layers)
    int n_nodes, int last_layer)
{
    int tid  = threadIdx.x;
    int wave = tid >> 6;
    int lane = tid & 63;
    int m = lane & 15, q = lane >> 4;
    int r0 = blockIdx.x * 64 + wave * 16;
    int rowm = r0 + m;
    int rowc = rowm < n_nodes ? rowm : n_nodes - 1;
    const unsigned short* ga = ghi + (size_t)rowc * 192;
    const unsigned short* gb = glo + (size_t)rowc * 192;

    float4v acc[4];
    #pragma unroll
    for (int ft = 0; ft < 4; ++ft) acc[ft] = (float4v){0.f, 0.f, 0.f, 0.f};

    #pragma unroll
    for (int ks = 0; ks < 6; ++ks) {
        int ko = ks * 32 + q * 8;
        short8 ah = *(const short8*)(ga + ko);
        short8 al = *(const short8*)(gb + ko);
        #pragma unroll
        for (int ft = 0; ft < 4; ++ft) {
            const unsigned short* wb = Wth + (size_t)(ft * 16 + m) * 192 + ko;
            const unsigned short* wl = Wtl + (size_t)(ft * 16 + m) * 192 + ko;
            short8 bh = *(const short8*)wb;
            short8 bl = *(const short8*)wl;
            acc[ft] = __builtin_amdgcn_mfma_f32_16x16x32_bf16(ah, bh, acc[ft], 0, 0, 0);
            acc[ft] = __builtin_amdgcn_mfma_f32_16x16x32_bf16(al, bh, acc[ft], 0, 0, 0);
            acc[ft] = __builtin_amdgcn_mfma_f32_16x16x32_bf16(ah, bl, acc[ft], 0, 0, 0);
        }
    }

    // D layout: col (f within tile) = lane&15 = m, row (within 16) = q*4 + r
    #pragma unroll
    for (int r = 0; r < 4; ++r) {
        int row = r0 + q * 4 + r;
        if (row < n_nodes) {
            if (last_layer) {
                #pragma unroll
                for (int ft = 0; ft < 4; ++ft)
                    out[(size_t)row * 64 + ft * 16 + m] = acc[ft][r];
            } else {
                #pragma unroll
                for (int ft = 0; ft < 4; ++ft)
                    hnext[(size_t)row * 64 + ft * 16 + m] = f2bf(acc[ft][r]);
            }
        }
    }
}

extern "C" void kernel_launch(void* const* d_in, const int* in_sizes, int n_in,
                              void* d_out, int out_size, void* d_ws, size_t ws_size,
                              hipStream_t stream)
{
    const float* feat   = (const float*)d_in[0];   // [N, 64]
    const float* pseudo = (const float*)d_in[1];   // [E, 2]
    const int*   rowptr = (const int*)d_in[2];     // [N+1]
    const int*   colind = (const int*)d_in[3];     // [E]
    const float* projW  = (const float*)d_in[4];   // [L, 2, 2]
    const float* projB  = (const float*)d_in[5];   // [L, 2]
    const float* fcW    = (const float*)d_in[6];   // [L, 64, 192]
    const float* mu     = (const float*)d_in[7];   // [L, 3, 2]
    const float* isg    = (const float*)d_in[8];   // [L, 3, 2]
    float* out = (float*)d_out;

    int n  = in_sizes[0] / FEAT;                        // 50000
    int e  = in_sizes[3];                               // 1.6M
    int n_layers = in_sizes[6] / (FEAT * NKERN * FEAT); // 3

    unsigned short* ghi = (unsigned short*)d_ws;                  // n*192
    unsigned short* glo = ghi + (size_t)n * 192;                  // n*192
    unsigned short* hbA = glo + (size_t)n * 192;                  // n*64
    unsigned short* hbB = hbA + (size_t)n * FEAT;                 // n*64
    unsigned short* Wth = hbB + (size_t)n * FEAT;                 // L*12288
    unsigned short* Wtl = Wth + (size_t)n_layers * 12288;         // L*12288
    float* wbuf = (float*)(Wtl + (size_t)n_layers * 12288);       // e*3

    dim3 blk(256);
    dim3 castGrid((n * FEAT / 4 + 255) / 256);
    dim3 wpGrid((n_layers * FEAT * 192 + 255) / 256);
    dim3 wkGrid((e + 255) / 256);
    dim3 aggGrid((n + 3) / 4);
    dim3 gemmGrid((n + 63) / 64);

    cast_kernel<<<castGrid, blk, 0, stream>>>(feat, hbA, n * FEAT / 4);
    wprep_kernel<<<wpGrid, blk, 0, stream>>>(fcW, Wth, Wtl, n_layers * FEAT * 192);

    const unsigned short* hin = hbA;
    for (int l = 0; l < n_layers; ++l) {
        int last = (l == n_layers - 1);
        unsigned short* hb_out = (l == 0) ? hbB : hbA;
        wk_kernel<<<wkGrid, blk, 0, stream>>>(
            pseudo, projW + (size_t)l * 4, projB + (size_t)l * 2,
            mu + (size_t)l * 6, isg + (size_t)l * 6, wbuf, e);
        agg_kernel<<<aggGrid, blk, 0, stream>>>(
            hin, rowptr, colind, wbuf, ghi, glo, n);
        gemm_kernel<<<gemmGrid, blk, 0, stream>>>(
            ghi, glo, Wth + (size_t)l * 12288, Wtl + (size_t)l * 12288,
            out, hb_out, n, last);
        hin = hb_out;
    }
}

// Round 9
// 254.692 us; speedup vs baseline: 1.7684x; 1.2475x over previous
//
#include <hip/hip_runtime.h>
#include <math.h>

#define FEAT 64
#define NKERN 3

typedef __attribute__((ext_vector_type(8))) short short8;
typedef __attribute__((ext_vector_type(4))) float float4v;

__device__ __forceinline__ unsigned short f2bf(float f) {
    unsigned int u = __float_as_uint(f);
    u = (u + 0x7fffu + ((u >> 16) & 1u)) >> 16;   // round-to-nearest-even
    return (unsigned short)u;
}
__device__ __forceinline__ float bf2f(unsigned short b) {
    return __uint_as_float(((unsigned int)b) << 16);
}

// feat (fp32) -> bf16, 4 elems/thread
__global__ __launch_bounds__(256) void cast_kernel(
    const float* __restrict__ x, unsigned short* __restrict__ y, int n4)
{
    int i = blockIdx.x * 256 + threadIdx.x;
    if (i >= n4) return;
    float4 v = ((const float4*)x)[i];
    ushort4 o;
    o.x = f2bf(v.x); o.y = f2bf(v.y); o.z = f2bf(v.z); o.w = f2bf(v.w);
    ((ushort4*)y)[i] = o;
}

// fcW[l][j][k*64+f] -> Bt hi/lo in MFMA B-fragment tiled order:
// frag element (f, jp): ft=f>>4, n=f&15, ks=jp>>5, q=(jp>>3)&3, e=jp&7
// dst = l*12288 + (((ft*6+ks)*4+q)*16 + n)*8 + e
__global__ __launch_bounds__(256) void wprep_kernel(
    const float* __restrict__ fcW,
    unsigned short* __restrict__ Bth, unsigned short* __restrict__ Btl,
    int total)  // L*64*192
{
    int idx = blockIdx.x * 256 + threadIdx.x;
    if (idx >= total) return;
    int l   = idx / (FEAT * 192);
    int rem = idx - l * (FEAT * 192);
    int f   = rem / 192;
    int jp  = rem - f * 192;
    int k = jp >> 6, j = jp & 63;
    float v = fcW[(size_t)l * 12288 + j * 192 + k * 64 + f];
    unsigned short hi = f2bf(v);
    int dst = l * 12288 +
              ((((f >> 4) * 6 + (jp >> 5)) * 4 + ((jp >> 3) & 3)) * 16 + (f & 15)) * 8 +
              (jp & 7);
    Bth[dst] = hi;
    Btl[dst] = f2bf(v - bf2f(hi));
}

// Per-edge Gaussian kernel weights for one layer: wbuf[e, k], k=0..2.
__global__ __launch_bounds__(256) void wk_kernel(
    const float* __restrict__ pseudo,  // [E, 2]
    const float* __restrict__ projW,   // [2,2] (din,dout)
    const float* __restrict__ projB,   // [2]
    const float* __restrict__ mu,      // [3,2]
    const float* __restrict__ isg,     // [3,2]
    float* __restrict__ wbuf,          // [E, 3]
    int n_edges)
{
    int e = blockIdx.x * 256 + threadIdx.x;
    if (e >= n_edges) return;
    float2 p = ((const float2*)pseudo)[e];
    float u0 = tanhf(fmaf(p.x, projW[0], fmaf(p.y, projW[2], projB[0])));
    float u1 = tanhf(fmaf(p.x, projW[1], fmaf(p.y, projW[3], projB[1])));
    float d0, d1, s0, s1;
    d0 = u0 - mu[0]; d1 = u1 - mu[1]; s0 = isg[0]; s1 = isg[1];
    float w0 = expf(-0.5f * (d0*d0*s0*s0 + d1*d1*s1*s1));
    d0 = u0 - mu[2]; d1 = u1 - mu[3]; s0 = isg[2]; s1 = isg[3];
    float w1 = expf(-0.5f * (d0*d0*s0*s0 + d1*d1*s1*s1));
    d0 = u0 - mu[4]; d1 = u1 - mu[5]; s0 = isg[4]; s1 = isg[5];
    float w2 = expf(-0.5f * (d0*d0*s0*s0 + d1*d1*s1*s1));
    wbuf[(size_t)e * 3 + 0] = w0;
    wbuf[(size_t)e * 3 + 1] = w1;
    wbuf[(size_t)e * 3 + 2] = w2;
}

// g[n][jp] = sum_{e in row(n)} wbuf[e,k] * h[colind[e], j], jp = k*64+j.
// One wave per node, lane = feature j; 32 gathers in flight. Output written
// bf16 directly in MFMA A-fragment tiled order:
//   A_t[t][ks][q][m][8], elem (node,jp): t=node>>4, m=node&15,
//   ks=jp>>5, q=(jp>>3)&3, e=jp&7.
__global__ __launch_bounds__(256, 6) void agg_kernel(
    const unsigned short* __restrict__ h,  // [N, 64] bf16
    const int*   __restrict__ rowptr,      // [N+1]
    const int*   __restrict__ colind,      // [E]
    const float* __restrict__ wbuf,        // [E, 3]
    unsigned short* __restrict__ Ah,       // [ntile][6][4][16][8] bf16
    int n_nodes)
{
    int lane = threadIdx.x & 63;
    int node = blockIdx.x * 4 + (threadIdx.x >> 6);
    if (node >= n_nodes) return;
    int nu  = __builtin_amdgcn_readfirstlane(node);
    int r0  = rowptr[nu];
    int deg = rowptr[nu + 1] - r0;   // fixed 32 in this problem

    float a0 = 0.f, a1 = 0.f, a2 = 0.f;
    if (deg == 32) {
        unsigned short v[32];
        #pragma unroll
        for (int i = 0; i < 32; ++i) {
            int cc = colind[r0 + i];             // uniform -> s_load
            v[i] = h[(size_t)cc * FEAT + lane];  // coalesced 128B gather
        }
        #pragma unroll
        for (int i = 0; i < 32; ++i) {
            const float* wp = wbuf + (size_t)(r0 + i) * 3;  // uniform s_load
            float vf = bf2f(v[i]);
            a0 = fmaf(wp[0], vf, a0);
            a1 = fmaf(wp[1], vf, a1);
            a2 = fmaf(wp[2], vf, a2);
        }
    } else {
        for (int i = 0; i < deg; ++i) {
            int cc = colind[r0 + i];
            float vf = bf2f(h[(size_t)cc * FEAT + lane]);
            const float* wp = wbuf + (size_t)(r0 + i) * 3;
            a0 = fmaf(wp[0], vf, a0);
            a1 = fmaf(wp[1], vf, a1);
            a2 = fmaf(wp[2], vf, a2);
        }
    }
    // tiled A store: jp = lane (+64, +128) -> ks0 = lane>>5 (+2, +4)
    int t = node >> 4, m = node & 15;
    size_t tb = (size_t)t * 6144 + (size_t)(lane >> 5) * 1024 +
                ((lane >> 3) & 3) * 128 + m * 8 + (lane & 7);
    Ah[tb]        = f2bf(a0);
    Ah[tb + 2048] = f2bf(a1);
    Ah[tb + 4096] = f2bf(a2);
}

// out[row, f] = sum_jp g[row][jp] * W[f][jp] via MFMA 16x16x32 bf16.
// Wave w owns ft=w (16 f cols): B-frags (hi+lo, 6 ks) preloaded into 48
// VGPRs from pre-tiled Bt (coalesced 1KB loads), resident across tiles.
// Per tile: 6 contiguous 1KB A loads + 12 MFMA. Grid-stride over tiles.
__global__ __launch_bounds__(256) void gemm_kernel(
    const unsigned short* __restrict__ Ah,   // [ntile][6][4][16][8]
    const unsigned short* __restrict__ Bth,  // this layer, frag-tiled
    const unsigned short* __restrict__ Btl,
    float* __restrict__ out,                 // [N,64] fp32 (last layer)
    unsigned short* __restrict__ hnext,      // [N,64] bf16 (mid layers)
    int n_nodes, int ntile, int last_layer)
{
    int tid  = threadIdx.x;
    int w    = tid >> 6;      // ft
    int lane = tid & 63;
    int q    = lane >> 4;
    int nn   = lane & 15;

    const unsigned short* bt0 = Bth + (((w * 6) * 4 + q) * 16 + nn) * 8;
    const unsigned short* bt1 = Btl + (((w * 6) * 4 + q) * 16 + nn) * 8;
    short8 bh[6], bl[6];
    #pragma unroll
    for (int ks = 0; ks < 6; ++ks) {
        bh[ks] = *(const short8*)(bt0 + ks * 512);   // ks stride = 4*16*8
        bl[ks] = *(const short8*)(bt1 + ks * 512);
    }

    for (int t = blockIdx.x; t < ntile; t += gridDim.x) {
        const unsigned short* at = Ah + (size_t)t * 6144 + q * 128 + nn * 8;
        float4v acc = (float4v){0.f, 0.f, 0.f, 0.f};
        #pragma unroll
        for (int ks = 0; ks < 6; ++ks) {
            short8 ah = *(const short8*)(at + ks * 1024);
            acc = __builtin_amdgcn_mfma_f32_16x16x32_bf16(ah, bh[ks], acc, 0, 0, 0);
            acc = __builtin_amdgcn_mfma_f32_16x16x32_bf16(ah, bl[ks], acc, 0, 0, 0);
        }
        // D: col f = w*16+nn (lane&15), row = t*16 + q*4 + r
        #pragma unroll
        for (int r = 0; r < 4; ++r) {
            int row = t * 16 + q * 4 + r;
            if (row < n_nodes) {
                if (last_layer)
                    out[(size_t)row * 64 + w * 16 + nn] = acc[r];
                else
                    hnext[(size_t)row * 64 + w * 16 + nn] = f2bf(acc[r]);
            }
        }
    }
}

extern "C" void kernel_launch(void* const* d_in, const int* in_sizes, int n_in,
                              void* d_out, int out_size, void* d_ws, size_t ws_size,
                              hipStream_t stream)
{
    const float* feat   = (const float*)d_in[0];   // [N, 64]
    const float* pseudo = (const float*)d_in[1];   // [E, 2]
    const int*   rowptr = (const int*)d_in[2];     // [N+1]
    const int*   colind = (const int*)d_in[3];     // [E]
    const float* projW  = (const float*)d_in[4];   // [L, 2, 2]
    const float* projB  = (const float*)d_in[5];   // [L, 2]
    const float* fcW    = (const float*)d_in[6];   // [L, 64, 192]
    const float* mu     = (const float*)d_in[7];   // [L, 3, 2]
    const float* isg    = (const float*)d_in[8];   // [L, 3, 2]
    float* out = (float*)d_out;

    int n  = in_sizes[0] / FEAT;                        // 50000
    int e  = in_sizes[3];                               // 1.6M
    int n_layers = in_sizes[6] / (FEAT * NKERN * FEAT); // 3
    int ntile = (n + 15) / 16;                          // 3125

    unsigned short* Ah  = (unsigned short*)d_ws;                  // ntile*6144
    unsigned short* hbA = Ah + (size_t)ntile * 6144;              // n*64
    unsigned short* hbB = hbA + (size_t)n * FEAT;                 // n*64
    unsigned short* Bth = hbB + (size_t)n * FEAT;                 // L*12288
    unsigned short* Btl = Bth + (size_t)n_layers * 12288;         // L*12288
    float* wbuf = (float*)(Btl + (size_t)n_layers * 12288);       // e*3

    dim3 blk(256);
    dim3 castGrid((n * FEAT / 4 + 255) / 256);
    dim3 wpGrid((n_layers * FEAT * 192 + 255) / 256);
    dim3 wkGrid((e + 255) / 256);
    dim3 aggGrid((n + 3) / 4);
    dim3 gemmGrid(1024);

    cast_kernel<<<castGrid, blk, 0, stream>>>(feat, hbA, n * FEAT / 4);
    wprep_kernel<<<wpGrid, blk, 0, stream>>>(fcW, Bth, Btl, n_layers * FEAT * 192);

    const unsigned short* hin = hbA;
    for (int l = 0; l < n_layers; ++l) {
        int last = (l == n_layers - 1);
        unsigned short* hb_out = (l == 0) ? hbB : hbA;
        wk_kernel<<<wkGrid, blk, 0, stream>>>(
            pseudo, projW + (size_t)l * 4, projB + (size_t)l * 2,
            mu + (size_t)l * 6, isg + (size_t)l * 6, wbuf, e);
        agg_kernel<<<aggGrid, blk, 0, stream>>>(
            hin, rowptr, colind, wbuf, Ah, n);
        gemm_kernel<<<gemmGrid, blk, 0, stream>>>(
            Ah, Bth + (size_t)l * 12288, Btl + (size_t)l * 12288,
            out, hb_out, n, ntile, last);
        hin = hb_out;
    }
}

// Round 10
// 245.715 us; speedup vs baseline: 1.8330x; 1.0365x over previous
//
#include <hip/hip_runtime.h>
#include <math.h>

#define FEAT 64
#define NKERN 3

typedef __attribute__((ext_vector_type(8))) short short8;
typedef __attribute__((ext_vector_type(4))) float float4v;

__device__ __forceinline__ unsigned short f2bf(float f) {
    unsigned int u = __float_as_uint(f);
    u = (u + 0x7fffu + ((u >> 16) & 1u)) >> 16;   // round-to-nearest-even
    return (unsigned short)u;
}
__device__ __forceinline__ float bf2f(unsigned short b) {
    return __uint_as_float(((unsigned int)b) << 16);
}

// feat (fp32) -> bf16, 4 elems/thread
__global__ __launch_bounds__(256) void cast_kernel(
    const float* __restrict__ x, unsigned short* __restrict__ y, int n4)
{
    int i = blockIdx.x * 256 + threadIdx.x;
    if (i >= n4) return;
    float4 v = ((const float4*)x)[i];
    ushort4 o;
    o.x = f2bf(v.x); o.y = f2bf(v.y); o.z = f2bf(v.z); o.w = f2bf(v.w);
    ((ushort4*)y)[i] = o;
}

// fcW[l][j][k*64+f] -> Bt hi/lo in MFMA B-fragment tiled order:
// frag element (f, jp): ft=f>>4, n=f&15, ks=jp>>5, q=(jp>>3)&3, e=jp&7
// dst = l*12288 + (((ft*6+ks)*4+q)*16 + n)*8 + e
__global__ __launch_bounds__(256) void wprep_kernel(
    const float* __restrict__ fcW,
    unsigned short* __restrict__ Bth, unsigned short* __restrict__ Btl,
    int total)  // L*64*192
{
    int idx = blockIdx.x * 256 + threadIdx.x;
    if (idx >= total) return;
    int l   = idx / (FEAT * 192);
    int rem = idx - l * (FEAT * 192);
    int f   = rem / 192;
    int jp  = rem - f * 192;
    int k = jp >> 6, j = jp & 63;
    float v = fcW[(size_t)l * 12288 + j * 192 + k * 64 + f];
    unsigned short hi = f2bf(v);
    int dst = l * 12288 +
              ((((f >> 4) * 6 + (jp >> 5)) * 4 + ((jp >> 3) & 3)) * 16 + (f & 15)) * 8 +
              (jp & 7);
    Bth[dst] = hi;
    Btl[dst] = f2bf(v - bf2f(hi));
}

// Per-edge Gaussian kernel weights for ALL layers in one pass (pseudo read once).
__global__ __launch_bounds__(256) void wk3_kernel(
    const float* __restrict__ pseudo,  // [E, 2]
    const float* __restrict__ projW,   // [L, 2, 2]
    const float* __restrict__ projB,   // [L, 2]
    const float* __restrict__ mu,      // [L, 3, 2]
    const float* __restrict__ isg,     // [L, 3, 2]
    float* __restrict__ wbuf3,         // [L, E, 3]
    int n_edges, int n_layers)
{
    int e = blockIdx.x * 256 + threadIdx.x;
    if (e >= n_edges) return;
    float2 p = ((const float2*)pseudo)[e];
    for (int l = 0; l < n_layers; ++l) {
        const float* pw = projW + l * 4;
        const float* pb = projB + l * 2;
        const float* m_ = mu  + l * 6;
        const float* s_ = isg + l * 6;
        float u0 = tanhf(fmaf(p.x, pw[0], fmaf(p.y, pw[2], pb[0])));
        float u1 = tanhf(fmaf(p.x, pw[1], fmaf(p.y, pw[3], pb[1])));
        float d0, d1, s0, s1;
        d0 = u0 - m_[0]; d1 = u1 - m_[1]; s0 = s_[0]; s1 = s_[1];
        float w0 = expf(-0.5f * (d0*d0*s0*s0 + d1*d1*s1*s1));
        d0 = u0 - m_[2]; d1 = u1 - m_[3]; s0 = s_[2]; s1 = s_[3];
        float w1 = expf(-0.5f * (d0*d0*s0*s0 + d1*d1*s1*s1));
        d0 = u0 - m_[4]; d1 = u1 - m_[5]; s0 = s_[4]; s1 = s_[5];
        float w2 = expf(-0.5f * (d0*d0*s0*s0 + d1*d1*s1*s1));
        float* wp = wbuf3 + ((size_t)l * n_edges + e) * 3;
        wp[0] = w0; wp[1] = w1; wp[2] = w2;
    }
}

// One fused layer: block = 16 waves = 16 nodes = one MFMA row-tile.
// Phase 1 (all 16 waves): per-node gather/accumulate (lane = feature j),
//   colind/wbuf via wave-uniform s_loads, 32 coalesced gathers in flight;
//   result written bf16 into LDS in MFMA A-fragment layout [6][4][16][8].
// Phase 2 (waves 0-3): wave w = f-tile ft; B hi/lo frags from pre-tiled,
//   L2-resident Bt (contiguous 16B loads); 6 ks x 2 MFMA; store h/out.
__global__ __launch_bounds__(1024) void layer_kernel(
    const unsigned short* __restrict__ h,    // [N, 64] bf16
    const int*   __restrict__ rowptr,        // [N+1]
    const int*   __restrict__ colind,        // [E]
    const float* __restrict__ wbuf,          // [E, 3] this layer
    const unsigned short* __restrict__ Bth,  // frag-tiled, this layer
    const unsigned short* __restrict__ Btl,
    float* __restrict__ out,                 // [N,64] fp32 (last layer)
    unsigned short* __restrict__ hnext,      // [N,64] bf16 (mid layers)
    int n_nodes, int last_layer)
{
    __shared__ unsigned short Atile[6144];   // [6][4][16][8] shorts, 12 KB
    int tid  = threadIdx.x;
    int wv   = tid >> 6;          // 0..15 = node row m within tile
    int lane = tid & 63;
    int node = blockIdx.x * 16 + wv;

    float a0 = 0.f, a1 = 0.f, a2 = 0.f;
    if (node < n_nodes) {
        int nu  = __builtin_amdgcn_readfirstlane(node);
        int r0  = rowptr[nu];
        int deg = rowptr[nu + 1] - r0;   // fixed 32 in this problem
        if (deg == 32) {
            unsigned short v[32];
            #pragma unroll
            for (int i = 0; i < 32; ++i) {
                int cc = colind[r0 + i];             // uniform -> s_load
                v[i] = h[(size_t)cc * FEAT + lane];  // coalesced 128B gather
            }
            #pragma unroll
            for (int i = 0; i < 32; ++i) {
                const float* wp = wbuf + (size_t)(r0 + i) * 3;  // uniform s_load
                float vf = bf2f(v[i]);
                a0 = fmaf(wp[0], vf, a0);
                a1 = fmaf(wp[1], vf, a1);
                a2 = fmaf(wp[2], vf, a2);
            }
        } else {
            for (int i = 0; i < deg; ++i) {
                int cc = colind[r0 + i];
                float vf = bf2f(h[(size_t)cc * FEAT + lane]);
                const float* wp = wbuf + (size_t)(r0 + i) * 3;
                a0 = fmaf(wp[0], vf, a0);
                a1 = fmaf(wp[1], vf, a1);
                a2 = fmaf(wp[2], vf, a2);
            }
        }
    }
    // A-frag LDS store: jp = lane (+64,+128) -> ks = jp>>5, q=(jp>>3)&3, e=jp&7
    int base = (lane >> 5) * 1024 + ((lane >> 3) & 3) * 128 + wv * 8 + (lane & 7);
    Atile[base]        = f2bf(a0);
    Atile[base + 2048] = f2bf(a1);
    Atile[base + 4096] = f2bf(a2);
    __syncthreads();

    if (wv < 4) {
        int w  = wv;            // f-tile
        int q  = lane >> 4;
        int nn = lane & 15;
        const unsigned short* bt0 = Bth + (((w * 6) * 4 + q) * 16 + nn) * 8;
        const unsigned short* bt1 = Btl + (((w * 6) * 4 + q) * 16 + nn) * 8;
        float4v acc = (float4v){0.f, 0.f, 0.f, 0.f};
        #pragma unroll
        for (int ks = 0; ks < 6; ++ks) {
            short8 ah = *(const short8*)&Atile[ks * 1024 + q * 128 + nn * 8];
            short8 bh = *(const short8*)(bt0 + ks * 512);
            short8 bl = *(const short8*)(bt1 + ks * 512);
            acc = __builtin_amdgcn_mfma_f32_16x16x32_bf16(ah, bh, acc, 0, 0, 0);
            acc = __builtin_amdgcn_mfma_f32_16x16x32_bf16(ah, bl, acc, 0, 0, 0);
        }
        // D: col f = w*16+nn, row = tile*16 + q*4 + r
        int t0 = blockIdx.x * 16;
        #pragma unroll
        for (int r = 0; r < 4; ++r) {
            int row = t0 + q * 4 + r;
            if (row < n_nodes) {
                if (last_layer)
                    out[(size_t)row * 64 + w * 16 + nn] = acc[r];
                else
                    hnext[(size_t)row * 64 + w * 16 + nn] = f2bf(acc[r]);
            }
        }
    }
}

extern "C" void kernel_launch(void* const* d_in, const int* in_sizes, int n_in,
                              void* d_out, int out_size, void* d_ws, size_t ws_size,
                              hipStream_t stream)
{
    const float* feat   = (const float*)d_in[0];   // [N, 64]
    const float* pseudo = (const float*)d_in[1];   // [E, 2]
    const int*   rowptr = (const int*)d_in[2];     // [N+1]
    const int*   colind = (const int*)d_in[3];     // [E]
    const float* projW  = (const float*)d_in[4];   // [L, 2, 2]
    const float* projB  = (const float*)d_in[5];   // [L, 2]
    const float* fcW    = (const float*)d_in[6];   // [L, 64, 192]
    const float* mu     = (const float*)d_in[7];   // [L, 3, 2]
    const float* isg    = (const float*)d_in[8];   // [L, 3, 2]
    float* out = (float*)d_out;

    int n  = in_sizes[0] / FEAT;                        // 50000
    int e  = in_sizes[3];                               // 1.6M
    int n_layers = in_sizes[6] / (FEAT * NKERN * FEAT); // 3

    unsigned short* hbA = (unsigned short*)d_ws;                  // n*64
    unsigned short* hbB = hbA + (size_t)n * FEAT;                 // n*64
    unsigned short* Bth = hbB + (size_t)n * FEAT;                 // L*12288
    unsigned short* Btl = Bth + (size_t)n_layers * 12288;         // L*12288
    float* wbuf3 = (float*)(Btl + (size_t)n_layers * 12288);      // L*e*3

    dim3 blk(256);
    dim3 castGrid((n * FEAT / 4 + 255) / 256);
    dim3 wpGrid((n_layers * FEAT * 192 + 255) / 256);
    dim3 wkGrid((e + 255) / 256);
    dim3 layerGrid((n + 15) / 16);
    dim3 layerBlk(1024);

    cast_kernel<<<castGrid, blk, 0, stream>>>(feat, hbA, n * FEAT / 4);
    wprep_kernel<<<wpGrid, blk, 0, stream>>>(fcW, Bth, Btl, n_layers * FEAT * 192);
    wk3_kernel<<<wkGrid, blk, 0, stream>>>(
        pseudo, projW, projB, mu, isg, wbuf3, e, n_layers);

    const unsigned short* hin = hbA;
    for (int l = 0; l < n_layers; ++l) {
        int last = (l == n_layers - 1);
        unsigned short* hb_out = (l == 0) ? hbB : hbA;
        layer_kernel<<<layerGrid, layerBlk, 0, stream>>>(
            hin, rowptr, colind, wbuf3 + (size_t)l * e * 3,
            Bth + (size_t)l * 12288, Btl + (size_t)l * 12288,
            out, hb_out, n, last);
        hin = hb_out;
    }
}